// Round 4
// baseline (565.940 us; speedup 1.0000x reference)
//
#include <hip/hip_runtime.h>
#include <hip/hip_bf16.h>
#include <cstdint>
#include <cstddef>

#define UNITS 1024
#define BDIM 32
#define TDIM 2048
#define M_TOT (BDIM*TDIM)   /* 65536 */
#define KDIM UNITS
#define NDIM UNITS
#define NPART 4              /* score partials = n-tiles of 256 */

#define K2LOG2E 2.885390081777927f   /* 2*log2(e): tanh(x) = 1 - 2/(exp2(x*K2LOG2E)+1) */

typedef __attribute__((ext_vector_type(8))) short bf16x8;           // 8 bf16 = 4 VGPRs
typedef __attribute__((ext_vector_type(8))) unsigned short ushort8;
typedef __attribute__((ext_vector_type(4))) float f32x4;

__device__ __forceinline__ unsigned short f2bf(float f) {
  unsigned u = __float_as_uint(f);
  u += 0x7fffu + ((u >> 16) & 1u);          // round-to-nearest-even
  return (unsigned short)(u >> 16);
}
__device__ __forceinline__ float bf2f(unsigned short h) {
  return __uint_as_float(((unsigned)h) << 16);
}

// ---------------- fp32 -> bf16 conversion (8 floats / thread / iter) --------
__global__ __launch_bounds__(256) void cvt_kernel(const float* __restrict__ src,
                                                  ushort* __restrict__ dst, int n8) {
  int i = blockIdx.x * blockDim.x + threadIdx.x;
  int stride = gridDim.x * blockDim.x;
  const float4* s4 = (const float4*)src;
  ushort8* d8 = (ushort8*)dst;
  for (; i < n8; i += stride) {
    float4 a = s4[2*i], b = s4[2*i+1];
    ushort8 o;
    o[0] = f2bf(a.x); o[1] = f2bf(a.y); o[2] = f2bf(a.z); o[3] = f2bf(a.w);
    o[4] = f2bf(b.x); o[5] = f2bf(b.y); o[6] = f2bf(b.z); o[7] = f2bf(b.w);
    d8[i] = o;                                   // one 16B store
  }
}

// ---------------- c[b,v] = W1_b[v] + W2_b[v] + dot(W2[v,:], hidden[b,:]) ----
__global__ __launch_bounds__(64) void prep_c_kernel(const float* __restrict__ W2w,
                                                    const float* __restrict__ hidden,
                                                    const float* __restrict__ W1b,
                                                    const float* __restrict__ W2b,
                                                    float* __restrict__ c) {
  int v = blockIdx.x;
  int l = threadIdx.x;
  float acc[BDIM];
  #pragma unroll
  for (int b = 0; b < BDIM; b++) acc[b] = 0.f;
  for (int u0 = 0; u0 < UNITS; u0 += 64) {
    float w = W2w[v*UNITS + u0 + l];           // coalesced over lanes
    #pragma unroll
    for (int b = 0; b < BDIM; b++) acc[b] += w * hidden[b*UNITS + u0 + l];
  }
  float bias = W1b[v] + W2b[v];
  #pragma unroll
  for (int b = 0; b < BDIM; b++) {
    float s = acc[b];
    #pragma unroll
    for (int off = 32; off > 0; off >>= 1) s += __shfl_xor(s, off);
    if (l == 0) c[b*UNITS + v] = s + bias;
  }
}

// ---------------- fused GEMM + tanh + V-dot -> partial scores ---------------
// R4: occupancy restructure. 128x256 tile, 8 waves of 64x64 (acc[4][4]=64
// regs -> total ~115 <= 128 -> 16 waves/CU = TWO independent blocks/CU whose
// barrier groups decorrelate stalls). BK=32, 1 phase per K-tile:
//   {4+4 ds_read_b128, 3 gll (stage tile tau+2), s_barrier,
//    setprio(1), 16 MFMA, setprio(0), vmcnt(3), s_barrier, sched_barrier(0)}
// LDS = 3-deep mod-3 rings, 72 KB: A-ring 3 x 8KB (128r x 32k) at 0,
// B-ring 3 x 16KB (256c x 32k) at ushort 12288. 2 blocks x 72 KB = 144 <= 160.
//
// Ledger: reads of tile tau all in phase tau (slot tau%3). Stage of tau+2
// issues in phase tau into slot (tau+2)%3, last read at phase tau-1 (>=1
// closing barrier earlier). vmcnt(3) at closing of tau retires phase tau-1's
// 3 gll -> tile tau+1 landed >=1 full phase before its read. Tail: vmcnt(0)
// at tau=30. Prologue stages tiles 0,1 (6 gll), vmcnt(3).
//
// Swizzle (2-way = free): phys k-slot = (k_slot + (row>>1)) & 3, staged via
// pre-rotated global source + linear gll dest; read prot = (lq+(lrow>>1))&3.
// Grid 2048 = 512 m-tiles x 4 n-tiles (nt-minor: XCD L2 pins one B n-panel).
#define GLL(g, l) __builtin_amdgcn_global_load_lds(                              \
    (const __attribute__((address_space(1))) void*)(g),                          \
    (__attribute__((address_space(3))) void*)(l), 16, 0, 0)

__global__ __launch_bounds__(512, 4) void gemm_score_kernel(
    const ushort* __restrict__ A,   // M x K bf16 (row-major)
    const ushort* __restrict__ W,   // N x K bf16 (row-major)
    const float* __restrict__ c,    // B x N
    const float* __restrict__ Vw,   // N
    float* __restrict__ score)      // NPART x M partials (each written once)
{
  __shared__ ushort shb[36864];   // 72 KB

  const int nt = blockIdx.x & 3;            // n-tile 0..3
  const int m0 = (blockIdx.x >> 2) * 128;
  const int n0 = nt * 256;
  const int bb = m0 >> 11;                  // 128 rows share one b (T=2048)
  const int tid = threadIdx.x;
  const int wave = tid >> 6;
  const int l = tid & 63;
  const int lrow = l & 15;                  // n/m within 16x16 frag
  const int lq = l >> 4;                    // k-quad (8 bf16 each)
  const int wm = (wave >> 2) * 64;          // wave m-offset (0 / 64)
  const int wn = (wave & 3) * 64;           // wave n-offset (0/64/128/192)

  // staging map: one gll-set = 8 waves x 64 lanes x 16B = 8KB linear region.
  // ushort off = tid*8 -> (row = tid>>2, phys = tid&3); content k-slot
  // s_g = (phys - (row>>1)) & 3  (4-slot rotation).
  const int s_g = ((tid & 3) - (tid >> 3)) & 3;
  const ushort* gA = A + (size_t)(m0 + (tid >> 2)) * KDIM + s_g * 8;
  const ushort* gB = W + (size_t)(n0 + (tid >> 2)) * KDIM + s_g * 8;  // B half0; half1 = +128*KDIM

  // fragment read map: phys = (lq + (row>>1)) & 3; wm/2, wn&64/2, i*8 == 0 mod 4
  const int prot = (lq + (lrow >> 1)) & 3;
  const int a_off = (wm + lrow) * 32 + prot * 8;                       // + slot*4096 + i*512
  const int b_off = 12288 + (wn >> 7) * 4096 + ((wn & 64) + lrow) * 32 + prot * 8; // + slot*8192 + j*512

  f32x4 acc[4][4];
  #pragma unroll
  for (int i = 0; i < 4; i++)
    #pragma unroll
    for (int j = 0; j < 4; j++) acc[i][j] = (f32x4)0.f;

  // stage one K-tile (A 8KB + B 16KB = 3 gll); advances pointers by 32 k
  #define STAGE(SL) {                                                           \
    GLL(gA, shb + (SL) * 4096 + wave * 512);                                    \
    GLL(gB, shb + 12288 + (SL) * 8192 + wave * 512);                            \
    GLL(gB + (size_t)128 * KDIM, shb + 12288 + (SL) * 8192 + 4096 + wave * 512);\
    gA += 32; gB += 32; }

  // one K-tile phase: reads slot SR, stages tile tau+2 into SW (if DO_ST),
  // 16 MFMA, counted vmcnt, closing barrier.
  #define PHASE(SR, SW, VM, DO_ST) {                                           \
    bf16x8 av[4], bv[4];                                                        \
    _Pragma("unroll")                                                           \
    for (int i = 0; i < 4; i++)                                                 \
      av[i] = *(const bf16x8*)(shb + (SR) * 4096 + a_off + i * 512);            \
    _Pragma("unroll")                                                           \
    for (int j = 0; j < 4; j++)                                                 \
      bv[j] = *(const bf16x8*)(shb + (SR) * 8192 + b_off + j * 512);            \
    if (DO_ST) STAGE(SW);                                                       \
    __builtin_amdgcn_s_barrier();                                               \
    __builtin_amdgcn_s_setprio(1);                                              \
    _Pragma("unroll")                                                           \
    for (int i = 0; i < 4; i++)                                                 \
      _Pragma("unroll")                                                         \
      for (int j = 0; j < 4; j++)                                               \
        acc[i][j] = __builtin_amdgcn_mfma_f32_16x16x32_bf16(av[i], bv[j],       \
                                                            acc[i][j], 0, 0, 0);\
    __builtin_amdgcn_s_setprio(0);                                              \
    if ((VM) == 3) asm volatile("s_waitcnt vmcnt(3)" ::: "memory");             \
    if ((VM) == 0) asm volatile("s_waitcnt vmcnt(0)" ::: "memory");             \
    __builtin_amdgcn_s_barrier();                                               \
    __builtin_amdgcn_sched_barrier(0);                                          \
  }

  // ---- prologue: stage tiles 0,1 (6 gll), wait tile 0 landed --------------
  STAGE(0);
  STAGE(1);
  asm volatile("s_waitcnt vmcnt(3)" ::: "memory");
  __builtin_amdgcn_s_barrier();
  __builtin_amdgcn_sched_barrier(0);

  // ---- main loop: tiles 0..29 (slots cycle 0,1,2; write slot = read+2) ----
  #pragma unroll 1
  for (int t = 0; t < 10; ++t) {
    PHASE(0, 2, 3, 1);
    PHASE(1, 0, 3, 1);
    PHASE(2, 1, 3, 1);
  }
  // ---- tail: tile 30 (drain stage(31)), tile 31 (nothing outstanding) -----
  PHASE(0, 0, 0, 0);
  PHASE(1, 0, -1, 0);

  #undef PHASE
  #undef STAGE

  // epilogue: score_partial = sum_n vw * tanh(C + c) = vws - 2 * sum vw*sigma
  float vw4[4], ck4[4];
  float vws = 0.f;
  #pragma unroll
  for (int j = 0; j < 4; j++) {
    int n = n0 + wn + j * 16 + lrow;
    float v = Vw[n];
    vw4[j] = v;
    vws += v;
    ck4[j] = c[bb * NDIM + n] * K2LOG2E;
  }
  float sacc[4][4];
  #pragma unroll
  for (int i = 0; i < 4; i++)
    #pragma unroll
    for (int r = 0; r < 4; r++) sacc[i][r] = 0.f;
  #pragma unroll
  for (int i = 0; i < 4; i++)
    #pragma unroll
    for (int j = 0; j < 4; j++)
      #pragma unroll
      for (int r = 0; r < 4; r++) {
        float t = __builtin_fmaf(acc[i][j][r], K2LOG2E, ck4[j]);
        float e = __builtin_amdgcn_exp2f(t);        // inf->rcp 0 (tanh=1); 0 (tanh=-1)
        float rr = __builtin_amdgcn_rcpf(e + 1.f);
        sacc[i][r] = __builtin_fmaf(vw4[j], rr, sacc[i][r]);
      }

  // reduce over 16 n-lanes of each quad, then across the 4 n-waves via LDS.
  // sred overlays A-ring slot 0; all DMA retired (vmcnt(0) at tile 30) and
  // last slot-0 read was tile 30, >=1 closing barrier ago.
  float* sred = (float*)shb;                      // 8 waves x 64 rows = 2 KB
  #pragma unroll
  for (int i = 0; i < 4; i++)
    #pragma unroll
    for (int r = 0; r < 4; r++) {
      float s = vws - 2.f * sacc[i][r];
      s += __shfl_xor(s, 1);
      s += __shfl_xor(s, 2);
      s += __shfl_xor(s, 4);
      s += __shfl_xor(s, 8);
      if (lrow == 0) sred[wave * 64 + i * 16 + lq * 4 + r] = s;
    }
  __syncthreads();
  if (tid < 128) {
    int mh = tid >> 6;            // m-half -> waves mh*4 .. mh*4+3
    int ml = tid & 63;
    float v = sred[(mh * 4 + 0) * 64 + ml] + sred[(mh * 4 + 1) * 64 + ml]
            + sred[(mh * 4 + 2) * 64 + ml] + sred[(mh * 4 + 3) * 64 + ml];
    score[(size_t)nt * M_TOT + m0 + tid] = v;
  }
}

// ---------------- softmax over T per b; sums the NPART partial slices ------
__global__ __launch_bounds__(256) void softmax_kernel(float* __restrict__ sc,
                                                      float* __restrict__ wout) {
  const int b = blockIdx.x;
  const int tid = threadIdx.x;
  float4* s4 = (float4*)(sc + (size_t)b * TDIM);
  float4 v0 = s4[2*tid], v1 = s4[2*tid+1];
  #pragma unroll
  for (int k = 1; k < NPART; k++) {
    const float4* p4 = (const float4*)(sc + (size_t)k * M_TOT + (size_t)b * TDIM);
    float4 u0 = p4[2*tid], u1 = p4[2*tid+1];
    v0.x += u0.x; v0.y += u0.y; v0.z += u0.z; v0.w += u0.w;
    v1.x += u1.x; v1.y += u1.y; v1.z += u1.z; v1.w += u1.w;
  }
  float mx = fmaxf(fmaxf(fmaxf(v0.x,v0.y),fmaxf(v0.z,v0.w)),
                   fmaxf(fmaxf(v1.x,v1.y),fmaxf(v1.z,v1.w)));
  #pragma unroll
  for (int off = 32; off > 0; off >>= 1) mx = fmaxf(mx, __shfl_xor(mx, off));
  __shared__ float redm[4];
  __shared__ float reds[4];
  if ((tid & 63) == 0) redm[tid >> 6] = mx;
  __syncthreads();
  mx = fmaxf(fmaxf(redm[0], redm[1]), fmaxf(redm[2], redm[3]));
  v0.x = __expf(v0.x - mx); v0.y = __expf(v0.y - mx);
  v0.z = __expf(v0.z - mx); v0.w = __expf(v0.w - mx);
  v1.x = __expf(v1.x - mx); v1.y = __expf(v1.y - mx);
  v1.z = __expf(v1.z - mx); v1.w = __expf(v1.w - mx);
  float sum = v0.x+v0.y+v0.z+v0.w+v1.x+v1.y+v1.z+v1.w;
  #pragma unroll
  for (int off = 32; off > 0; off >>= 1) sum += __shfl_xor(sum, off);
  if ((tid & 63) == 0) reds[tid >> 6] = sum;
  __syncthreads();
  sum = reds[0]+reds[1]+reds[2]+reds[3];
  float inv = 1.f / sum;
  v0.x *= inv; v0.y *= inv; v0.z *= inv; v0.w *= inv;
  v1.x *= inv; v1.y *= inv; v1.z *= inv; v1.w *= inv;
  s4[2*tid] = v0; s4[2*tid+1] = v1;                 // ws copy for context pass
  float4* w4 = (float4*)(wout + (size_t)b * TDIM);  // d_out weights
  w4[2*tid] = v0; w4[2*tid+1] = v1;
}

// ---------------- context[b,u] = sum_t w[b,t]*x[b,t,u]  (exact, no atomics) -
// grid (8 u-chunks of 128, 32 b); 256 threads = 16 u-threads x 16 t-rows
__global__ __launch_bounds__(256) void context_kernel(const ushort* __restrict__ xb,
                                                      const float* __restrict__ wgt,
                                                      float* __restrict__ ctx) {
  const int uc = blockIdx.x;
  const int b = blockIdx.y;
  const int tid = threadIdx.x;
  __shared__ float wl[TDIM];
  {
    const float4* wsrc = (const float4*)(wgt + (size_t)b * TDIM);
    float4* wdst = (float4*)wl;
    wdst[tid] = wsrc[tid];
    wdst[tid + 256] = wsrc[tid + 256];
  }
  __syncthreads();
  const int ut = tid & 15;         // 16 threads x ushort8 = 128 u
  const int tr = tid >> 4;         // 16 t-rows per sweep
  const ushort* xp = xb + (size_t)b * TDIM * UNITS + uc * 128 + ut * 8;
  float a8[8];
  #pragma unroll
  for (int e = 0; e < 8; e++) a8[e] = 0.f;
  for (int t = tr; t < TDIM; t += 64) {            // 4-way unrolled over stride 16
    ushort8 x0 = *(const ushort8*)(xp + (size_t)(t     ) * UNITS);
    ushort8 x1 = *(const ushort8*)(xp + (size_t)(t + 16) * UNITS);
    ushort8 x2 = *(const ushort8*)(xp + (size_t)(t + 32) * UNITS);
    ushort8 x3 = *(const ushort8*)(xp + (size_t)(t + 48) * UNITS);
    float w0 = wl[t], w1 = wl[t+16], w2 = wl[t+32], w3 = wl[t+48];
    #pragma unroll
    for (int e = 0; e < 8; e++) {
      a8[e] += w0 * bf2f(x0[e]);
      a8[e] += w1 * bf2f(x1[e]);
      a8[e] += w2 * bf2f(x2[e]);
      a8[e] += w3 * bf2f(x3[e]);
    }
  }
  // reduce over the 4 t-rows within each wave
  #pragma unroll
  for (int e = 0; e < 8; e++) {
    a8[e] += __shfl_xor(a8[e], 16);
    a8[e] += __shfl_xor(a8[e], 32);
  }
  __shared__ float red[512];
  const int wave = tid >> 6;
  const int l = tid & 63;
  if (l < 16) {
    #pragma unroll
    for (int e = 0; e < 8; e++) red[wave * 128 + l * 8 + e] = a8[e];
  }
  __syncthreads();
  if (tid < 128) {
    float v = red[tid] + red[128 + tid] + red[256 + tid] + red[384 + tid];
    ctx[(size_t)b * UNITS + uc * 128 + tid] = v;
  }
}

extern "C" void kernel_launch(void* const* d_in, const int* in_sizes, int n_in,
                              void* d_out, int out_size, void* d_ws, size_t ws_size,
                              hipStream_t stream) {
  const float* x   = (const float*)d_in[0];
  const float* hid = (const float*)d_in[1];
  const float* W1w = (const float*)d_in[2];
  const float* W1b = (const float*)d_in[3];
  const float* W2w = (const float*)d_in[4];
  const float* W2b = (const float*)d_in[5];
  const float* Vw  = (const float*)d_in[6];
  // d_in[7] (V_b) intentionally unused: softmax is shift-invariant.
  float* out = (float*)d_out;

  char* ws = (char*)d_ws;
  ushort* xb   = (ushort*)ws;                                        // 128 MB
  ushort* w1b  = (ushort*)(ws + (size_t)M_TOT*KDIM*2);               // 2 MB
  float*  cbuf = (float*)(ws + (size_t)M_TOT*KDIM*2 + (size_t)NDIM*KDIM*2); // 128 KB
  float*  score= (float*)((char*)cbuf + (size_t)BDIM*NDIM*4);        // NPART x 256 KB partials

  cvt_kernel<<<4096, 256, 0, stream>>>(x, xb, M_TOT*KDIM/8);
  cvt_kernel<<<512, 256, 0, stream>>>(W1w, w1b, NDIM*KDIM/8);
  prep_c_kernel<<<NDIM, 64, 0, stream>>>(W2w, hid, W1b, W2b, cbuf);
  gemm_score_kernel<<<M_TOT/128 * NPART, 512, 0, stream>>>(xb, w1b, cbuf, Vw, score);
  softmax_kernel<<<BDIM, 256, 0, stream>>>(score, out + (size_t)BDIM*UNITS);
  context_kernel<<<dim3(8, BDIM), 256, 0, stream>>>(xb, score, out);
}

// Round 6
// 564.222 us; speedup vs baseline: 1.0030x; 1.0030x over previous
//
#include <hip/hip_runtime.h>
#include <hip/hip_bf16.h>
#include <cstdint>
#include <cstddef>

#define UNITS 1024
#define BDIM 32
#define TDIM 2048
#define M_TOT (BDIM*TDIM)   /* 65536 */
#define KDIM UNITS
#define NDIM UNITS
#define NPART 4              /* score partials = n-tiles of 256 */

#define K2LOG2E 2.885390081777927f   /* 2*log2(e): tanh(x) = 1 - 2/(exp2(x*K2LOG2E)+1) */

typedef __attribute__((ext_vector_type(8))) short bf16x8;           // 8 bf16 = 4 VGPRs
typedef __attribute__((ext_vector_type(8))) unsigned short ushort8;
typedef __attribute__((ext_vector_type(4))) float f32x4;

__device__ __forceinline__ unsigned short f2bf(float f) {
  unsigned u = __float_as_uint(f);
  u += 0x7fffu + ((u >> 16) & 1u);          // round-to-nearest-even
  return (unsigned short)(u >> 16);
}
__device__ __forceinline__ float bf2f(unsigned short h) {
  return __uint_as_float(((unsigned)h) << 16);
}

// ---------------- fp32 -> bf16 conversion (8 floats / thread / iter) --------
__global__ __launch_bounds__(256) void cvt_kernel(const float* __restrict__ src,
                                                  ushort* __restrict__ dst, int n8) {
  int i = blockIdx.x * blockDim.x + threadIdx.x;
  int stride = gridDim.x * blockDim.x;
  const float4* s4 = (const float4*)src;
  ushort8* d8 = (ushort8*)dst;
  for (; i < n8; i += stride) {
    float4 a = s4[2*i], b = s4[2*i+1];
    ushort8 o;
    o[0] = f2bf(a.x); o[1] = f2bf(a.y); o[2] = f2bf(a.z); o[3] = f2bf(a.w);
    o[4] = f2bf(b.x); o[5] = f2bf(b.y); o[6] = f2bf(b.z); o[7] = f2bf(b.w);
    d8[i] = o;                                   // one 16B store
  }
}

// ---------------- c[b,v] = W1_b[v] + W2_b[v] + dot(W2[v,:], hidden[b,:]) ----
__global__ __launch_bounds__(64) void prep_c_kernel(const float* __restrict__ W2w,
                                                    const float* __restrict__ hidden,
                                                    const float* __restrict__ W1b,
                                                    const float* __restrict__ W2b,
                                                    float* __restrict__ c) {
  int v = blockIdx.x;
  int l = threadIdx.x;
  float acc[BDIM];
  #pragma unroll
  for (int b = 0; b < BDIM; b++) acc[b] = 0.f;
  for (int u0 = 0; u0 < UNITS; u0 += 64) {
    float w = W2w[v*UNITS + u0 + l];           // coalesced over lanes
    #pragma unroll
    for (int b = 0; b < BDIM; b++) acc[b] += w * hidden[b*UNITS + u0 + l];
  }
  float bias = W1b[v] + W2b[v];
  #pragma unroll
  for (int b = 0; b < BDIM; b++) {
    float s = acc[b];
    #pragma unroll
    for (int off = 32; off > 0; off >>= 1) s += __shfl_xor(s, off);
    if (l == 0) c[b*UNITS + v] = s + bias;
  }
}

// ---------------- fused GEMM + tanh + V-dot -> partial scores ---------------
// R5: R3 geometry (256x256 tile, 8 waves 2Mx4N of 128x64, BK=64, 4-slot
// 16KB half-tile rings, rotation swizzle) + ONE-PHASE-AHEAD REGISTER
// PREFETCH: each phase issues the NEXT phase's ds_reads (rotating reg sets
// avlo/avhi/bv0/bv1), then MFMAs fragments read a full phase earlier, gated
// by counted lgkmcnt(4|8) that leaves the prefetch in flight under the MFMA.
//
// Phase stream per tile tau (c0/c1 = k-halves, slots s=(2tau+c)&3):
//  P1: rd avhi(c0) | stage Ac1(tau+1) | MFMA avlo*bv0 -> acc[0..3] | vmcnt(6)
//  P2: rd bv1+avlo(c1) | stage Bc1(tau+1) | MFMA avhi*bv0 -> acc[4..7]
//  P3: rd avhi(c1) | stage Ac0(tau+2) | MFMA avlo*bv1 -> acc[0..3] | vmcnt(6)
//  P4: rd bv0+avlo(c0,tau+1) | stage Bc0(tau+2) | MFMA avhi*bv1 -> acc[4..7]
// Checkpoints (vmcnt(6)+barrier) publish: end-P1 -> c1(tau) readable at P2;
// end-P3 -> c0(tau+1) readable at P4. Every prefetch issues AFTER the
// checkpoint barrier publishing its slot. Slot overwrites are >=1 closing
// barrier after the last reader's lgkm gate. Tail drains vmcnt 6->4->0.
// Grid 1024 = 256 m-tiles x 4 n-tiles (nt-minor: XCD L2 pins one B n-panel).
#define GLL(g, l) __builtin_amdgcn_global_load_lds(                              \
    (const __attribute__((address_space(1))) void*)(g),                          \
    (__attribute__((address_space(3))) void*)(l), 16, 0, 0)

__global__ __launch_bounds__(512, 2) void gemm_score_kernel(
    const ushort* __restrict__ A,   // M x K bf16 (row-major)
    const ushort* __restrict__ W,   // N x K bf16 (row-major)
    const float* __restrict__ c,    // B x N
    const float* __restrict__ Vw,   // N
    float* __restrict__ score)      // NPART x M partials (each written once)
{
  __shared__ ushort shb[65536];   // 128 KB: A-ring 4x16KB | B-ring 4x16KB

  const int nt = blockIdx.x & 3;            // n-tile 0..3
  const int m0 = (blockIdx.x >> 2) * 256;
  const int n0 = nt * 256;
  const int bb = m0 >> 11;                  // 256 rows share one b (T=2048)
  const int tid = threadIdx.x;
  const int wave = tid >> 6;
  const int l = tid & 63;
  const int lrow = l & 15;                  // row/col within 16x16 frag
  const int lq = l >> 4;                    // k-quad (8 bf16 each)
  const int wm = (wave >> 2) * 128;         // wave m-offset (0 / 128)
  const int wn = (wave & 3) * 64;           // wave n-offset (0/64/128/192)

  // staging map (R3): gll region linear, ushort off = q*4096 + tid*8 ->
  // (row = q*128 + tid>>2, phys = tid&3); content k-slot = (phys-(row>>1))&3
  const int s_g = ((tid & 3) - (tid >> 3)) & 3;
  const ushort* sA = A + (size_t)(m0 + (tid >> 2)) * KDIM + s_g * 8;
  const ushort* sB = W + (size_t)(n0 + (tid >> 2)) * KDIM + s_g * 8;

  // fragment read map: phys = (lq + (row>>1)) & 3
  const int prot = (lq + (lrow >> 1)) & 3;
  const int a_off = (wm + lrow) * 32 + prot * 8;
  const int b_off = (wn + lrow) * 32 + prot * 8;

  f32x4 acc[8][4];
  #pragma unroll
  for (int i = 0; i < 8; i++)
    #pragma unroll
    for (int j = 0; j < 4; j++) acc[i][j] = (f32x4)0.f;

  bf16x8 avlo[4], avhi[4], bv0[4], bv1[4];

  #define RDA(SL, I) (*(const bf16x8*)(shb + (SL) * 8192 + a_off + (I) * 512))
  #define RDB(SL, J) (*(const bf16x8*)(shb + 32768 + (SL) * 8192 + b_off + (J) * 512))

  // stage one 16KB half-tile (2 gll): KO = k element offset (multiple of 32)
  #define STA(SL, KO) { const ushort* g_ = sA + (KO);                           \
    GLL(g_, shb + (SL) * 8192 + wave * 512);                                    \
    GLL(g_ + (size_t)128 * KDIM, shb + (SL) * 8192 + 4096 + wave * 512); }
  #define STB(SL, KO) { const ushort* g_ = sB + (KO);                           \
    GLL(g_, shb + 32768 + (SL) * 8192 + wave * 512);                            \
    GLL(g_ + (size_t)128 * KDIM, shb + 32768 + (SL) * 8192 + 4096 + wave * 512); }
  #define STN ((void)0)

  #define VMW(VM) {                                                             \
    if ((VM) == 6) asm volatile("s_waitcnt vmcnt(6)" ::: "memory");             \
    if ((VM) == 4) asm volatile("s_waitcnt vmcnt(4)" ::: "memory");             \
    if ((VM) == 0) asm volatile("s_waitcnt vmcnt(0)" ::: "memory"); }

  // PH1: prefetch avhi from A-slot RS; MFMA avlo x BV -> acc[0..3]
  #define PH1(RS, BV, STx, VM) {                                                \
    avhi[0] = RDA(RS, 4); avhi[1] = RDA(RS, 5);                                 \
    avhi[2] = RDA(RS, 6); avhi[3] = RDA(RS, 7);                                 \
    STx;                                                                        \
    __builtin_amdgcn_sched_barrier(0);                                          \
    __builtin_amdgcn_s_barrier();                                               \
    asm volatile("s_waitcnt lgkmcnt(4)" ::: "memory");                          \
    __builtin_amdgcn_s_setprio(1);                                              \
    _Pragma("unroll")                                                           \
    for (int i = 0; i < 4; i++)                                                 \
      _Pragma("unroll")                                                         \
      for (int j = 0; j < 4; j++)                                               \
        acc[i][j] = __builtin_amdgcn_mfma_f32_16x16x32_bf16(avlo[i], BV[j],     \
                                                            acc[i][j], 0, 0, 0);\
    __builtin_amdgcn_s_setprio(0);                                              \
    VMW(VM);                                                                    \
    __builtin_amdgcn_s_barrier();                                               \
    __builtin_amdgcn_sched_barrier(0); }

  // PH2: prefetch BNEW from B-slot RSB + avlo from A-slot RSA (if DO_RD);
  //      MFMA avhi x BCUR -> acc[4..7]
  #define PH2(RSA, RSB, BNEW, BCUR, STx, VM, DO_RD) {                           \
    if (DO_RD) {                                                                \
      BNEW[0] = RDB(RSB, 0); BNEW[1] = RDB(RSB, 1);                             \
      BNEW[2] = RDB(RSB, 2); BNEW[3] = RDB(RSB, 3);                             \
      avlo[0] = RDA(RSA, 0); avlo[1] = RDA(RSA, 1);                             \
      avlo[2] = RDA(RSA, 2); avlo[3] = RDA(RSA, 3);                             \
    }                                                                           \
    STx;                                                                        \
    __builtin_amdgcn_sched_barrier(0);                                          \
    __builtin_amdgcn_s_barrier();                                               \
    if (DO_RD) { asm volatile("s_waitcnt lgkmcnt(8)" ::: "memory"); }           \
    else       { asm volatile("s_waitcnt lgkmcnt(0)" ::: "memory"); }           \
    __builtin_amdgcn_s_setprio(1);                                              \
    _Pragma("unroll")                                                           \
    for (int i = 0; i < 4; i++)                                                 \
      _Pragma("unroll")                                                         \
      for (int j = 0; j < 4; j++)                                               \
        acc[4 + i][j] = __builtin_amdgcn_mfma_f32_16x16x32_bf16(avhi[i],        \
                                         BCUR[j], acc[4 + i][j], 0, 0, 0);      \
    __builtin_amdgcn_s_setprio(0);                                              \
    VMW(VM);                                                                    \
    __builtin_amdgcn_s_barrier();                                               \
    __builtin_amdgcn_sched_barrier(0); }

  // ---- prologue: stage c0(0),c1(0),c0(1); publish c0(0); initial frags ----
  STA(0, 0);  STB(0, 0);
  STA(1, 32); STB(1, 32);
  STA(2, 64); STB(2, 64);
  asm volatile("s_waitcnt vmcnt(8)" ::: "memory");   // c0(0) landed
  __builtin_amdgcn_s_barrier();
  __builtin_amdgcn_sched_barrier(0);
  bv0[0] = RDB(0, 0); bv0[1] = RDB(0, 1); bv0[2] = RDB(0, 2); bv0[3] = RDB(0, 3);
  avlo[0] = RDA(0, 0); avlo[1] = RDA(0, 1); avlo[2] = RDA(0, 2); avlo[3] = RDA(0, 3);
  __builtin_amdgcn_sched_barrier(0);

  // ---- main loop: tile pairs (even: slots 0,1 / odd: slots 2,3), t=0..13 --
  #pragma unroll 1
  for (int t = 0; t < 7; ++t) {
    // even tile tau: c0=slot0, c1=slot1; next c0 = slot2
    PH1(0, bv0, STA(3, 96),  6);
    PH2(1, 1, bv1, bv0, STB(3, 96), -1, 1);
    PH1(1, bv1, STA(0, 128), 6);
    PH2(2, 2, bv0, bv1, STB(0, 128), -1, 1);
    // odd tile tau+1: c0=slot2, c1=slot3; next c0 = slot0
    PH1(2, bv0, STA(1, 160), 6);
    PH2(3, 3, bv1, bv0, STB(1, 160), -1, 1);
    PH1(3, bv1, STA(2, 192), 6);
    PH2(0, 0, bv0, bv1, STB(2, 192), -1, 1);
    sA += 128; sB += 128;
  }
  // ---- tail: tile 14 (stages c1(15) only), tile 15 (no stages) ------------
  PH1(0, bv0, STA(3, 96), 6);
  PH2(1, 1, bv1, bv0, STB(3, 96), -1, 1);
  PH1(1, bv1, STN, 4);                      // c0(15) published
  PH2(2, 2, bv0, bv1, STN, -1, 1);
  PH1(2, bv0, STN, 0);                      // c1(15) published
  PH2(3, 3, bv1, bv0, STN, -1, 1);
  PH1(3, bv1, STN, -1);
  PH2(0, 0, bv0, bv1, STN, -1, 0);          // MFMA only

  #undef PH1
  #undef PH2
  #undef STA
  #undef STB
  #undef STN
  #undef VMW
  #undef RDA
  #undef RDB

  // epilogue: score_partial = sum_n vw * tanh(C + c) = vws - 2 * sum vw*sigma
  float vw4[4], ck4[4];
  float vws = 0.f;
  #pragma unroll
  for (int j = 0; j < 4; j++) {
    int n = n0 + wn + j * 16 + lrow;
    float v = Vw[n];
    vw4[j] = v;
    vws += v;
    ck4[j] = c[bb * NDIM + n] * K2LOG2E;
  }
  float sacc[8][4];
  #pragma unroll
  for (int i = 0; i < 8; i++)
    #pragma unroll
    for (int r = 0; r < 4; r++) sacc[i][r] = 0.f;
  #pragma unroll
  for (int i = 0; i < 8; i++)
    #pragma unroll
    for (int j = 0; j < 4; j++)
      #pragma unroll
      for (int r = 0; r < 4; r++) {
        float t = __builtin_fmaf(acc[i][j][r], K2LOG2E, ck4[j]);
        float e = __builtin_amdgcn_exp2f(t);        // inf->rcp 0 (tanh=1); 0 (tanh=-1)
        float rr = __builtin_amdgcn_rcpf(e + 1.f);
        sacc[i][r] = __builtin_fmaf(vw4[j], rr, sacc[i][r]);
      }

  // reduce over 16 n-lanes of each quad, then across the 4 n-waves via LDS.
  // sred overlays A-ring slot 0: all gll retired (vmcnt(0) in tail), and the
  // last slot-0 ds_read (tile-14 P1 prefetch) completed many barriers ago.
  float* sred = (float*)shb;                      // 8 waves x 128 rows = 4 KB
  #pragma unroll
  for (int i = 0; i < 8; i++)
    #pragma unroll
    for (int r = 0; r < 4; r++) {
      float s = vws - 2.f * sacc[i][r];
      s += __shfl_xor(s, 1);
      s += __shfl_xor(s, 2);
      s += __shfl_xor(s, 4);
      s += __shfl_xor(s, 8);
      if (lrow == 0) sred[wave * 128 + i * 16 + lq * 4 + r] = s;
    }
  __syncthreads();
  if (tid < 256) {
    int mh = tid >> 7;            // which 128-row half -> waves mh*4 .. mh*4+3
    int ml = tid & 127;
    float v = sred[mh * 512 + ml] + sred[mh * 512 + 128 + ml]
            + sred[mh * 512 + 256 + ml] + sred[mh * 512 + 384 + ml];
    score[(size_t)nt * M_TOT + m0 + tid] = v;
  }
}

// ---------------- softmax over T per b; sums the NPART partial slices ------
__global__ __launch_bounds__(256) void softmax_kernel(float* __restrict__ sc,
                                                      float* __restrict__ wout) {
  const int b = blockIdx.x;
  const int tid = threadIdx.x;
  float4* s4 = (float4*)(sc + (size_t)b * TDIM);
  float4 v0 = s4[2*tid], v1 = s4[2*tid+1];
  #pragma unroll
  for (int k = 1; k < NPART; k++) {
    const float4* p4 = (const float4*)(sc + (size_t)k * M_TOT + (size_t)b * TDIM);
    float4 u0 = p4[2*tid], u1 = p4[2*tid+1];
    v0.x += u0.x; v0.y += u0.y; v0.z += u0.z; v0.w += u0.w;
    v1.x += u1.x; v1.y += u1.y; v1.z += u1.z; v1.w += u1.w;
  }
  float mx = fmaxf(fmaxf(fmaxf(v0.x,v0.y),fmaxf(v0.z,v0.w)),
                   fmaxf(fmaxf(v1.x,v1.y),fmaxf(v1.z,v1.w)));
  #pragma unroll
  for (int off = 32; off > 0; off >>= 1) mx = fmaxf(mx, __shfl_xor(mx, off));
  __shared__ float redm[4];
  __shared__ float reds[4];
  if ((tid & 63) == 0) redm[tid >> 6] = mx;
  __syncthreads();
  mx = fmaxf(fmaxf(redm[0], redm[1]), fmaxf(redm[2], redm[3]));
  v0.x = __expf(v0.x - mx); v0.y = __expf(v0.y - mx);
  v0.z = __expf(v0.z - mx); v0.w = __expf(v0.w - mx);
  v1.x = __expf(v1.x - mx); v1.y = __expf(v1.y - mx);
  v1.z = __expf(v1.z - mx); v1.w = __expf(v1.w - mx);
  float sum = v0.x+v0.y+v0.z+v0.w+v1.x+v1.y+v1.z+v1.w;
  #pragma unroll
  for (int off = 32; off > 0; off >>= 1) sum += __shfl_xor(sum, off);
  if ((tid & 63) == 0) reds[tid >> 6] = sum;
  __syncthreads();
  sum = reds[0]+reds[1]+reds[2]+reds[3];
  float inv = 1.f / sum;
  v0.x *= inv; v0.y *= inv; v0.z *= inv; v0.w *= inv;
  v1.x *= inv; v1.y *= inv; v1.z *= inv; v1.w *= inv;
  s4[2*tid] = v0; s4[2*tid+1] = v1;                 // ws copy for context pass
  float4* w4 = (float4*)(wout + (size_t)b * TDIM);  // d_out weights
  w4[2*tid] = v0; w4[2*tid+1] = v1;
}

// ---------------- context[b,u] = sum_t w[b,t]*x[b,t,u]  (exact, no atomics) -
// grid (8 u-chunks of 128, 32 b); 256 threads = 16 u-threads x 16 t-rows
__global__ __launch_bounds__(256) void context_kernel(const ushort* __restrict__ xb,
                                                      const float* __restrict__ wgt,
                                                      float* __restrict__ ctx) {
  const int uc = blockIdx.x;
  const int b = blockIdx.y;
  const int tid = threadIdx.x;
  __shared__ float wl[TDIM];
  {
    const float4* wsrc = (const float4*)(wgt + (size_t)b * TDIM);
    float4* wdst = (float4*)wl;
    wdst[tid] = wsrc[tid];
    wdst[tid + 256] = wsrc[tid + 256];
  }
  __syncthreads();
  const int ut = tid & 15;         // 16 threads x ushort8 = 128 u
  const int tr = tid >> 4;         // 16 t-rows per sweep
  const ushort* xp = xb + (size_t)b * TDIM * UNITS + uc * 128 + ut * 8;
  float a8[8];
  #pragma unroll
  for (int e = 0; e < 8; e++) a8[e] = 0.f;
  for (int t = tr; t < TDIM; t += 64) {            // 4-way unrolled over stride 16
    ushort8 x0 = *(const ushort8*)(xp + (size_t)(t     ) * UNITS);
    ushort8 x1 = *(const ushort8*)(xp + (size_t)(t + 16) * UNITS);
    ushort8 x2 = *(const ushort8*)(xp + (size_t)(t + 32) * UNITS);
    ushort8 x3 = *(const ushort8*)(xp + (size_t)(t + 48) * UNITS);
    float w0 = wl[t], w1 = wl[t+16], w2 = wl[t+32], w3 = wl[t+48];
    #pragma unroll
    for (int e = 0; e < 8; e++) {
      a8[e] += w0 * bf2f(x0[e]);
      a8[e] += w1 * bf2f(x1[e]);
      a8[e] += w2 * bf2f(x2[e]);
      a8[e] += w3 * bf2f(x3[e]);
    }
  }
  // reduce over the 4 t-rows within each wave
  #pragma unroll
  for (int e = 0; e < 8; e++) {
    a8[e] += __shfl_xor(a8[e], 16);
    a8[e] += __shfl_xor(a8[e], 32);
  }
  __shared__ float red[512];
  const int wave = tid >> 6;
  const int l = tid & 63;
  if (l < 16) {
    #pragma unroll
    for (int e = 0; e < 8; e++) red[wave * 128 + l * 8 + e] = a8[e];
  }
  __syncthreads();
  if (tid < 128) {
    float v = red[tid] + red[128 + tid] + red[256 + tid] + red[384 + tid];
    ctx[(size_t)b * UNITS + uc * 128 + tid] = v;
  }
}

extern "C" void kernel_launch(void* const* d_in, const int* in_sizes, int n_in,
                              void* d_out, int out_size, void* d_ws, size_t ws_size,
                              hipStream_t stream) {
  const float* x   = (const float*)d_in[0];
  const float* hid = (const float*)d_in[1];
  const float* W1w = (const float*)d_in[2];
  const float* W1b = (const float*)d_in[3];
  const float* W2w = (const float*)d_in[4];
  const float* W2b = (const float*)d_in[5];
  const float* Vw  = (const float*)d_in[6];
  // d_in[7] (V_b) intentionally unused: softmax is shift-invariant.
  float* out = (float*)d_out;

  char* ws = (char*)d_ws;
  ushort* xb   = (ushort*)ws;                                        // 128 MB
  ushort* w1b  = (ushort*)(ws + (size_t)M_TOT*KDIM*2);               // 2 MB
  float*  cbuf = (float*)(ws + (size_t)M_TOT*KDIM*2 + (size_t)NDIM*KDIM*2); // 128 KB
  float*  score= (float*)((char*)cbuf + (size_t)BDIM*NDIM*4);        // NPART x 256 KB partials

  cvt_kernel<<<4096, 256, 0, stream>>>(x, xb, M_TOT*KDIM/8);
  cvt_kernel<<<512, 256, 0, stream>>>(W1w, w1b, NDIM*KDIM/8);
  prep_c_kernel<<<NDIM, 64, 0, stream>>>(W2w, hid, W1b, W2b, cbuf);
  gemm_score_kernel<<<M_TOT/256 * NPART, 512, 0, stream>>>(xb, w1b, cbuf, Vw, score);
  softmax_kernel<<<BDIM, 256, 0, stream>>>(score, out + (size_t)BDIM*UNITS);
  context_kernel<<<dim3(8, BDIM), 256, 0, stream>>>(xb, score, out);
}